// Round 1
// baseline (26565.714 us; speedup 1.0000x reference)
//
#include <hip/hip_runtime.h>

// Problem constants (reference: B,T,V,E,H = 16,64,32000,256,1024)
#define B_ 16
#define T_ 64
#define V_ 32000
#define E_ 256
#define H_ 1024
#define G4_ (4 * H_)      // 4096 gate width
#define KE_ (E_ + H_)     // 1280 encoder GEMM K
#define KD_ (E_ + 2*H_)   // 2304 decoder GEMM K
#define NKS_ 32           // k-splits for enc/dec GEMMs
#define KSE_ (KE_ / NKS_) // 40  rows per k-split (encoder)
#define KSD_ (KD_ / NKS_) // 72  rows per k-split (decoder)

typedef unsigned short ushort_t;
typedef unsigned int uint_t;

__device__ __forceinline__ float b2f(ushort_t u) {
    return __uint_as_float(((uint_t)u) << 16);
}
__device__ __forceinline__ ushort_t f2b(float f) {
    uint_t u = __float_as_uint(f);
    u = (u + 0x7fffu + ((u >> 16) & 1u)) >> 16;   // round-to-nearest-even
    return (ushort_t)u;
}
__device__ __forceinline__ float sigf(float x) {
    return 1.f / (1.f + expf(-x));
}

// ---------------------------------------------------------------------------
// Split-K semaphore helpers. Producer blocks: threadfence + one release-add
// per block. Consumers: acquire-spin until target, then syncthreads.
// Deadlock-safe because every grid used with these fits fully resident:
//  - 512-block grids, 256 thr, __launch_bounds__(256,2) -> VGPR<=256 ->
//    >=2 blocks/CU x 256 CUs = >=512 resident.
//  - 256-block grids -> 1 block/CU trivially resident.
// ---------------------------------------------------------------------------
__device__ __forceinline__ void block_arrive(int* cnt) {
    __threadfence();
    __syncthreads();
    if (threadIdx.x == 0)
        __hip_atomic_fetch_add(cnt, 1, __ATOMIC_RELEASE, __HIP_MEMORY_SCOPE_AGENT);
}
__device__ __forceinline__ void block_wait(int* cnt, int target) {
    if (threadIdx.x == 0) {
        while (__hip_atomic_load(cnt, __ATOMIC_ACQUIRE, __HIP_MEMORY_SCOPE_AGENT) < target)
            __builtin_amdgcn_s_sleep(2);
    }
    __syncthreads();
}
__device__ __forceinline__ void grid_barrier(int* cnt, int target) {
    block_arrive(cnt);
    block_wait(cnt, target);
}

// ---------------------------------------------------------------------------
// Zero-init fp32 state (hbuf x2, c, attn = 4*16384 floats) + 256 counters.
// ---------------------------------------------------------------------------
__global__ __launch_bounds__(256) void init_kernel(float* __restrict__ state,
                                                   int* __restrict__ cnts)
{
    const int i = blockIdx.x * 256 + threadIdx.x;
    if (i < 4 * B_ * H_) state[i] = 0.f;
    if (i < 256) cnts[i] = 0;
}

// ---------------------------------------------------------------------------
// Encoder step: split-K GEMM (grid 512 = 16 colchunk x 32 ksplit) with
// fused gates tail (blocks ks>=28 spin until all 512 partials stored, then
// run the 64-block gates domain). x-loads vectorized float4 over k; FMA
// order per k identical to the scalar version.
// ---------------------------------------------------------------------------
__global__ __launch_bounds__(256, 2) void enc_step_kernel(
    const float* __restrict__ emb, const int* __restrict__ enc_in,
    const float* __restrict__ Wk, const float* __restrict__ bias,
    const int* __restrict__ enc_len, const float* __restrict__ h_in,
    float* __restrict__ h_out, float* __restrict__ c,
    float* __restrict__ memory, float* __restrict__ zpart,
    int* __restrict__ cnt, int t)
{
    const int tid = threadIdx.x;
    const int cc = blockIdx.x & 15;
    const int ks = blockIdx.x >> 4;           // 0..31
    const int col = cc * 256 + tid;
    const int k0 = ks * KSE_;

    int vidx[16];
    #pragma unroll
    for (int b = 0; b < 16; ++b) vidx[b] = enc_in[b * T_ + t];

    float acc[16];
    #pragma unroll
    for (int b = 0; b < 16; ++b) acc[b] = 0.f;

    for (int g = 0; g < KSE_ / 4; ++g) {
        const int k = k0 + g * 4;
        const float* wp = Wk + (size_t)k * G4_ + col;
        const float w0 = wp[0];
        const float w1 = wp[G4_];
        const float w2 = wp[2 * G4_];
        const float w3 = wp[3 * G4_];
        if (k < E_) {     // groups never straddle: boundaries are x4
            #pragma unroll
            for (int b = 0; b < 16; ++b) {
                const float4 xv = *(const float4*)(emb + (size_t)vidx[b] * E_ + k);
                acc[b] = fmaf(xv.x, w0, acc[b]);
                acc[b] = fmaf(xv.y, w1, acc[b]);
                acc[b] = fmaf(xv.z, w2, acc[b]);
                acc[b] = fmaf(xv.w, w3, acc[b]);
            }
        } else {
            const float* hp = h_in + (k - E_);
            #pragma unroll
            for (int b = 0; b < 16; ++b) {
                const float4 xv = *(const float4*)(hp + b * H_);
                acc[b] = fmaf(xv.x, w0, acc[b]);
                acc[b] = fmaf(xv.y, w1, acc[b]);
                acc[b] = fmaf(xv.z, w2, acc[b]);
                acc[b] = fmaf(xv.w, w3, acc[b]);
            }
        }
    }
    #pragma unroll
    for (int b = 0; b < 16; ++b)
        zpart[(size_t)(ks * 16 + b) * G4_ + col] = acc[b];

    block_arrive(cnt);
    if (ks < 28) return;                       // 448 producer-only blocks exit
    block_wait(cnt, 512);

    // ---- fused gates (64 tail blocks = 16384 threads, 1 elem each) ----
    const int tb = (ks - 28) * 16 + cc;        // 0..63
    const int idx = tb * 256 + tid;
    const int b = idx >> 10, hu = idx & 1023;
    float z[4];
    #pragma unroll
    for (int g = 0; g < 4; ++g) {
        float s0 = bias[g * H_ + hu], s1 = 0.f, s2 = 0.f, s3 = 0.f;
        #pragma unroll
        for (int kss = 0; kss < NKS_; kss += 4) {
            s0 += zpart[(size_t)((kss + 0) * 16 + b) * G4_ + g * H_ + hu];
            s1 += zpart[(size_t)((kss + 1) * 16 + b) * G4_ + g * H_ + hu];
            s2 += zpart[(size_t)((kss + 2) * 16 + b) * G4_ + g * H_ + hu];
            s3 += zpart[(size_t)((kss + 3) * 16 + b) * G4_ + g * H_ + hu];
        }
        z[g] = (s0 + s1) + (s2 + s3);
    }
    const float cold = c[b * H_ + hu];
    const float cn = cold * sigf(z[2] + 1.f) + sigf(z[0]) * tanhf(z[1]);
    const float hn = tanhf(cn) * sigf(z[3]);
    const bool valid = t < enc_len[b];
    h_out[b * H_ + hu] = valid ? hn : h_in[b * H_ + hu];
    c[b * H_ + hu]     = valid ? cn : cold;
    memory[((size_t)b * T_ + t) * H_ + hu] = valid ? hn : 0.f;
}

// ---------------------------------------------------------------------------
// keys = memory[1024,1024] @ Wm. Grid 256 = (64 rowtile, 4 cc), float4 k.
// ---------------------------------------------------------------------------
__global__ __launch_bounds__(256) void keys_gemm_kernel(
    const float* __restrict__ memory, const float* __restrict__ Wm,
    float* __restrict__ keys)
{
    const int rt = blockIdx.x >> 2;
    const int cc = blockIdx.x & 3;
    const int col = cc * 256 + threadIdx.x;
    float acc[16];
    #pragma unroll
    for (int m = 0; m < 16; ++m) acc[m] = 0.f;
    for (int g = 0; g < H_ / 4; ++g) {
        const int k = g * 4;
        const float* wp = Wm + (size_t)k * H_ + col;
        const float w0 = wp[0], w1 = wp[H_], w2 = wp[2 * H_], w3 = wp[3 * H_];
        const float* mp = memory + (size_t)(rt * 16) * H_ + k;
        #pragma unroll
        for (int m = 0; m < 16; ++m) {
            const float4 xv = *(const float4*)(mp + (size_t)m * H_);
            acc[m] = fmaf(xv.x, w0, acc[m]);
            acc[m] = fmaf(xv.y, w1, acc[m]);
            acc[m] = fmaf(xv.z, w2, acc[m]);
            acc[m] = fmaf(xv.w, w3, acc[m]);
        }
    }
    #pragma unroll
    for (int m = 0; m < 16; ++m)
        keys[(size_t)(rt * 16 + m) * H_ + col] = acc[m];
}

// ---------------------------------------------------------------------------
// Decoder step: split-K GEMM (K=2304, grid 512) with fused gates tail.
// ---------------------------------------------------------------------------
__global__ __launch_bounds__(256, 2) void dec_step_kernel(
    const float* __restrict__ emb, const int* __restrict__ dec_in,
    const float* __restrict__ Wk, const float* __restrict__ bias,
    const float* __restrict__ attn, const float* __restrict__ h_in,
    float* __restrict__ h_out, float* __restrict__ c,
    float* __restrict__ zpart, int* __restrict__ cnt, int t)
{
    const int tid = threadIdx.x;
    const int cc = blockIdx.x & 15;
    const int ks = blockIdx.x >> 4;           // 0..31
    const int col = cc * 256 + tid;
    const int k0 = ks * KSD_;

    int vidx[16];
    #pragma unroll
    for (int b = 0; b < 16; ++b) vidx[b] = dec_in[b * T_ + t];

    float acc[16];
    #pragma unroll
    for (int b = 0; b < 16; ++b) acc[b] = 0.f;

    for (int g = 0; g < KSD_ / 4; ++g) {
        const int k = k0 + g * 4;
        const float* wp = Wk + (size_t)k * G4_ + col;
        const float w0 = wp[0];
        const float w1 = wp[G4_];
        const float w2 = wp[2 * G4_];
        const float w3 = wp[3 * G4_];
        if (k < E_) {
            #pragma unroll
            for (int b = 0; b < 16; ++b) {
                const float4 xv = *(const float4*)(emb + (size_t)vidx[b] * E_ + k);
                acc[b] = fmaf(xv.x, w0, acc[b]);
                acc[b] = fmaf(xv.y, w1, acc[b]);
                acc[b] = fmaf(xv.z, w2, acc[b]);
                acc[b] = fmaf(xv.w, w3, acc[b]);
            }
        } else {
            const float* xb = (k < E_ + H_) ? (attn + (k - E_))
                                            : (h_in + (k - E_ - H_));
            #pragma unroll
            for (int b = 0; b < 16; ++b) {
                const float4 xv = *(const float4*)(xb + b * H_);
                acc[b] = fmaf(xv.x, w0, acc[b]);
                acc[b] = fmaf(xv.y, w1, acc[b]);
                acc[b] = fmaf(xv.z, w2, acc[b]);
                acc[b] = fmaf(xv.w, w3, acc[b]);
            }
        }
    }
    #pragma unroll
    for (int b = 0; b < 16; ++b)
        zpart[(size_t)(ks * 16 + b) * G4_ + col] = acc[b];

    block_arrive(cnt);
    if (ks < 28) return;
    block_wait(cnt, 512);

    // ---- fused gates (no masking on carry) ----
    const int tb = (ks - 28) * 16 + cc;
    const int idx = tb * 256 + tid;
    const int b = idx >> 10, hu = idx & 1023;
    float z[4];
    #pragma unroll
    for (int g = 0; g < 4; ++g) {
        float s0 = bias[g * H_ + hu], s1 = 0.f, s2 = 0.f, s3 = 0.f;
        #pragma unroll
        for (int kss = 0; kss < NKS_; kss += 4) {
            s0 += zpart[(size_t)((kss + 0) * 16 + b) * G4_ + g * H_ + hu];
            s1 += zpart[(size_t)((kss + 1) * 16 + b) * G4_ + g * H_ + hu];
            s2 += zpart[(size_t)((kss + 2) * 16 + b) * G4_ + g * H_ + hu];
            s3 += zpart[(size_t)((kss + 3) * 16 + b) * G4_ + g * H_ + hu];
        }
        z[g] = (s0 + s1) + (s2 + s3);
    }
    const float cold = c[b * H_ + hu];
    const float cn = cold * sigf(z[2] + 1.f) + sigf(z[0]) * tanhf(z[1]);
    const float hn = tanhf(cn) * sigf(z[3]);
    h_out[b * H_ + hu] = hn;
    c[b * H_ + hu] = cn;
}

// ---------------------------------------------------------------------------
// Fused attention mega-kernel: q-GEMM partials -> q finish -> scores ->
// softmax+context -> attn-out GEMM partials -> finish. Grid 256 (all
// resident), 5 counting grid-barriers on one counter (targets 256..1280).
// Replaces 6 kernels + 5 dispatch gaps per decoder step.
// ---------------------------------------------------------------------------
__global__ __launch_bounds__(256, 2) void attn_mega_kernel(
    const float* __restrict__ h2, const float* __restrict__ Wq,
    float* __restrict__ qpart, float* __restrict__ q,
    const float* __restrict__ keys, const float* __restrict__ v_att,
    float* __restrict__ scores, const float* __restrict__ memory,
    const int* __restrict__ enc_len, float* __restrict__ ctx,
    const float* __restrict__ attnK, float* __restrict__ apart,
    const int* __restrict__ dec_len, float* __restrict__ attn_state,
    float* __restrict__ dec_out, int* __restrict__ cnt, int t)
{
    const int tid = threadIdx.x;
    const int blk = blockIdx.x;
    __shared__ float al[T_];
    __shared__ float red[4];

    // ---- Phase A: q partials. 256 blocks = 4 cc x 64 ksplit (16 k each)
    {
        const int cc = blk & 3, ks = blk >> 2;
        const int col = cc * 256 + tid;
        const int k0 = ks * 16;
        float acc[16];
        #pragma unroll
        for (int b = 0; b < 16; ++b) acc[b] = 0.f;
        #pragma unroll
        for (int g = 0; g < 4; ++g) {
            const int k = k0 + g * 4;
            const float* wp = Wq + (size_t)k * H_ + col;
            const float w0 = wp[0], w1 = wp[H_], w2 = wp[2 * H_], w3 = wp[3 * H_];
            #pragma unroll
            for (int b = 0; b < 16; ++b) {
                const float4 xv = *(const float4*)(h2 + b * H_ + k);
                acc[b] = fmaf(xv.x, w0, acc[b]);
                acc[b] = fmaf(xv.y, w1, acc[b]);
                acc[b] = fmaf(xv.z, w2, acc[b]);
                acc[b] = fmaf(xv.w, w3, acc[b]);
            }
        }
        #pragma unroll
        for (int b = 0; b < 16; ++b)
            qpart[(size_t)(ks * 16 + b) * H_ + col] = acc[b];
    }
    grid_barrier(cnt, 256);

    // ---- Phase A2: q finish (blocks 0..63)
    if (blk < 64) {
        const int idx = blk * 256 + tid;
        const int b = idx >> 10, col = idx & 1023;
        float s0 = 0.f, s1 = 0.f, s2 = 0.f, s3 = 0.f;
        #pragma unroll
        for (int ks = 0; ks < 64; ks += 4) {
            s0 += qpart[(size_t)((ks + 0) * 16 + b) * H_ + col];
            s1 += qpart[(size_t)((ks + 1) * 16 + b) * H_ + col];
            s2 += qpart[(size_t)((ks + 2) * 16 + b) * H_ + col];
            s3 += qpart[(size_t)((ks + 3) * 16 + b) * H_ + col];
        }
        q[idx] = (s0 + s1) + (s2 + s3);
    }
    grid_barrier(cnt, 512);

    // ---- Phase B: scores, 4 (b,t) tasks per block
    #pragma unroll
    for (int i = 0; i < 4; ++i) {
        const int task = blk * 4 + i;
        const int b = task >> 6, tt = task & 63;
        const float* kp = keys + ((size_t)b * T_ + tt) * H_;
        const float* qp = q + b * H_;
        float s = 0.f;
        #pragma unroll
        for (int j = 0; j < 4; ++j) {
            const int h = tid + j * 256;
            s += tanhf(kp[h] + qp[h]) * v_att[h];
        }
        #pragma unroll
        for (int off = 32; off; off >>= 1) s += __shfl_xor(s, off);
        if ((tid & 63) == 0) red[tid >> 6] = s;
        __syncthreads();
        if (tid == 0) scores[b * T_ + tt] = (red[0] + red[1]) + (red[2] + red[3]);
        __syncthreads();
    }
    grid_barrier(cnt, 768);

    // ---- Phase C: masked softmax + context (blocks 0..63)
    if (blk < 64) {
        const int b = blk >> 2, cc = blk & 3;
        if (tid < 64) {
            const int len = enc_len[b];
            float s = (tid < len) ? scores[b * T_ + tid] : -1e9f;
            float m = s;
            #pragma unroll
            for (int off = 32; off; off >>= 1) m = fmaxf(m, __shfl_xor(m, off));
            const float e = expf(s - m);
            float sum = e;
            #pragma unroll
            for (int off = 32; off; off >>= 1) sum += __shfl_xor(sum, off);
            al[tid] = e / sum;
        }
        __syncthreads();
        const int col = cc * 256 + tid;
        const float* mp = memory + (size_t)b * T_ * H_ + col;
        float a0 = 0.f, a1 = 0.f, a2 = 0.f, a3 = 0.f;
        #pragma unroll
        for (int t2 = 0; t2 < T_; t2 += 4) {
            a0 = fmaf(al[t2 + 0], mp[(size_t)(t2 + 0) * H_], a0);
            a1 = fmaf(al[t2 + 1], mp[(size_t)(t2 + 1) * H_], a1);
            a2 = fmaf(al[t2 + 2], mp[(size_t)(t2 + 2) * H_], a2);
            a3 = fmaf(al[t2 + 3], mp[(size_t)(t2 + 3) * H_], a3);
        }
        ctx[b * H_ + col] = (a0 + a1) + (a2 + a3);
    }
    grid_barrier(cnt, 1024);

    // ---- Phase D: attn-out partials: [h2|ctx](K=2048) @ attnK, 64 ksplits
    {
        const int cc = blk & 3, ks = blk >> 2;
        const int col = cc * 256 + tid;
        const int k0 = ks * 32;
        float acc[16];
        #pragma unroll
        for (int b = 0; b < 16; ++b) acc[b] = 0.f;
        #pragma unroll
        for (int g = 0; g < 8; ++g) {
            const int k = k0 + g * 4;
            const float* wp = attnK + (size_t)k * H_ + col;
            const float w0 = wp[0], w1 = wp[H_], w2 = wp[2 * H_], w3 = wp[3 * H_];
            const float* xb = (k < H_) ? (h2 + k) : (ctx + (k - H_));
            #pragma unroll
            for (int b = 0; b < 16; ++b) {
                const float4 xv = *(const float4*)(xb + b * H_);
                acc[b] = fmaf(xv.x, w0, acc[b]);
                acc[b] = fmaf(xv.y, w1, acc[b]);
                acc[b] = fmaf(xv.z, w2, acc[b]);
                acc[b] = fmaf(xv.w, w3, acc[b]);
            }
        }
        #pragma unroll
        for (int b = 0; b < 16; ++b)
            apart[(size_t)(ks * 16 + b) * H_ + col] = acc[b];
    }
    grid_barrier(cnt, 1280);

    // ---- Phase E: finish attn2 -> attn state + dec_out (blocks 0..63)
    if (blk < 64) {
        const int idx = blk * 256 + tid;
        const int b = idx >> 10, col = idx & 1023;
        float s0 = 0.f, s1 = 0.f, s2 = 0.f, s3 = 0.f;
        #pragma unroll
        for (int ks = 0; ks < 64; ks += 4) {
            s0 += apart[(size_t)((ks + 0) * 16 + b) * H_ + col];
            s1 += apart[(size_t)((ks + 1) * 16 + b) * H_ + col];
            s2 += apart[(size_t)((ks + 2) * 16 + b) * H_ + col];
            s3 += apart[(size_t)((ks + 3) * 16 + b) * H_ + col];
        }
        const float s = (s0 + s1) + (s2 + s3);
        attn_state[b * H_ + col] = s;
        dec_out[((size_t)b * T_ + t) * H_ + col] = (t >= dec_len[b]) ? 0.f : s;
    }
}

// ---------------------------------------------------------------------------
// logits = dec_out(fp32 [1024,1024]) @ out_kernel(fp32 [1024,32000]) -> fp32.
// Split-bf16: D = ah*bh + ah*bl + al*bh. MFMA 16x16x32_bf16, 64x64 tile.
// (unchanged from the verified version)
// ---------------------------------------------------------------------------
typedef __attribute__((ext_vector_type(8))) short short8;
typedef __attribute__((ext_vector_type(4))) float float4v;

__global__ __launch_bounds__(256) void logits_kernel(
    const float* __restrict__ A, const float* __restrict__ Bw,
    float* __restrict__ out)
{
    __shared__ __align__(16) ushort_t Ah[64][40];
    __shared__ __align__(16) ushort_t Al[64][40];
    __shared__ __align__(16) ushort_t Bh[64][40];   // transposed: [n][k]
    __shared__ __align__(16) ushort_t Bl[64][40];
    const int tid = threadIdx.x;
    const int m0 = blockIdx.x * 64;
    const int n0 = blockIdx.y * 64;
    const int wv = tid >> 6, lane = tid & 63;
    const int ml = lane & 15, quad = lane >> 4;

    float4v acc[4];
    #pragma unroll
    for (int nn = 0; nn < 4; ++nn) acc[nn] = (float4v){0.f, 0.f, 0.f, 0.f};

    for (int kb = 0; kb < 1024; kb += 32) {
        __syncthreads();
        {   // stage A: 64 rows x 32 k fp32 -> hi/lo bf16
            const int r = tid >> 2, c0 = (tid & 3) * 8;
            const float* ap = A + (size_t)(m0 + r) * 1024 + kb + c0;
            #pragma unroll
            for (int i = 0; i < 8; ++i) {
                const float f = ap[i];
                const ushort_t hi = f2b(f);
                Ah[r][c0 + i] = hi;
                Al[r][c0 + i] = f2b(f - b2f(hi));
            }
        }
        {   // stage B transposed: coalesced rows, fp32 -> hi/lo bf16
            const int cB = tid & 63, kq = tid >> 6;
            #pragma unroll
            for (int i = 0; i < 8; ++i) {
                const int k = kq * 8 + i;
                const float f = Bw[(size_t)(kb + k) * V_ + n0 + cB];
                const ushort_t hi = f2b(f);
                Bh[cB][k] = hi;
                Bl[cB][k] = f2b(f - b2f(hi));
            }
        }
        __syncthreads();
        const short8 afh = *(const short8*)&Ah[wv * 16 + ml][quad * 8];
        const short8 afl = *(const short8*)&Al[wv * 16 + ml][quad * 8];
        #pragma unroll
        for (int nn = 0; nn < 4; ++nn) {
            const short8 bfh = *(const short8*)&Bh[nn * 16 + ml][quad * 8];
            const short8 bfl = *(const short8*)&Bl[nn * 16 + ml][quad * 8];
            acc[nn] = __builtin_amdgcn_mfma_f32_16x16x32_bf16(afh, bfh, acc[nn], 0, 0, 0);
            acc[nn] = __builtin_amdgcn_mfma_f32_16x16x32_bf16(afh, bfl, acc[nn], 0, 0, 0);
            acc[nn] = __builtin_amdgcn_mfma_f32_16x16x32_bf16(afl, bfh, acc[nn], 0, 0, 0);
        }
    }
    #pragma unroll
    for (int nn = 0; nn < 4; ++nn) {
        #pragma unroll
        for (int rg = 0; rg < 4; ++rg) {
            const int row = m0 + wv * 16 + quad * 4 + rg;
            const int colo = n0 + nn * 16 + ml;
            out[(size_t)row * V_ + colo] = acc[nn][rg];
        }
    }
}

// ---------------------------------------------------------------------------
extern "C" void kernel_launch(void* const* d_in, const int* in_sizes, int n_in,
                              void* d_out, int out_size, void* d_ws, size_t ws_size,
                              hipStream_t stream) {
    (void)in_sizes; (void)n_in; (void)out_size; (void)ws_size;
    const int*   enc_in  = (const int*)d_in[0];
    const int*   dec_in  = (const int*)d_in[1];
    const int*   enc_len = (const int*)d_in[2];
    const int*   dec_len = (const int*)d_in[3];
    const float* emb     = (const float*)d_in[4];
    const float* encK    = (const float*)d_in[5];
    const float* encB    = (const float*)d_in[6];
    const float* decK    = (const float*)d_in[7];
    const float* decB    = (const float*)d_in[8];
    const float* Wm      = (const float*)d_in[9];
    const float* Wq      = (const float*)d_in[10];
    const float* v_att   = (const float*)d_in[11];
    const float* attnK   = (const float*)d_in[12];
    const float* outK    = (const float*)d_in[13];
    float* out = (float*)d_out;

    // fp32 workspace layout (~21.4 MB + 1KB counters). qpart/apart alias
    // zpart (phases are sequential: zpart dead after fused gates; qpart dead
    // after phase A2; apart lives in zpart's second half).
    float* hbuf    = (float*)d_ws;                      // 2 x [16,1024]
    float* cbuf    = hbuf + 2 * B_ * H_;                // [16,1024]
    float* attn    = cbuf + B_ * H_;                    // [16,1024]
    float* ctx     = attn + B_ * H_;                    // [16,1024]
    float* q       = ctx + B_ * H_;                     // [16,1024]
    float* scores  = q + B_ * H_;                       // [16,64]
    float* memory  = scores + B_ * T_;                  // [16,64,1024]
    float* keys    = memory + (size_t)B_ * T_ * H_;     // [16,64,1024]
    float* dec_out = keys + (size_t)B_ * T_ * H_;       // [1024,1024]
    float* zpart   = dec_out + (size_t)B_ * T_ * H_;    // [32][16][4096] = 8MB
    float* qpart   = zpart;                             // [64][16][1024] alias
    float* apart   = zpart + (size_t)64 * B_ * H_;      // [64][16][1024] alias
    int*   cnts    = (int*)(zpart + (size_t)NKS_ * B_ * G4_);  // 256 ints

    // zero fp32 recurrent state (ws poisoned 0xAA) + semaphore counters
    init_kernel<<<256, 256, 0, stream>>>((float*)d_ws, cnts);

    for (int t = 0; t < T_; ++t) {
        float* h_in  = hbuf + (t & 1) * B_ * H_;
        float* h_out = hbuf + ((t + 1) & 1) * B_ * H_;
        enc_step_kernel<<<512, 256, 0, stream>>>(emb, enc_in, encK, encB, enc_len,
                                                 h_in, h_out, cbuf, memory, zpart,
                                                 cnts + t, t);
    }
    keys_gemm_kernel<<<256, 256, 0, stream>>>(memory, Wm, keys);

    for (int t = 0; t < T_; ++t) {
        float* h_in = hbuf + (t & 1) * B_ * H_;
        float* h2   = hbuf + ((t + 1) & 1) * B_ * H_;
        dec_step_kernel<<<512, 256, 0, stream>>>(emb, dec_in, decK, decB, attn,
                                                 h_in, h2, cbuf, zpart,
                                                 cnts + 64 + t, t);
        attn_mega_kernel<<<256, 256, 0, stream>>>(h2, Wq, qpart, q, keys, v_att,
                                                  scores, memory, enc_len, ctx,
                                                  attnK, apart, dec_len, attn,
                                                  dec_out, cnts + 128 + t, t);
    }

    logits_kernel<<<dim3(16, 500), 256, 0, stream>>>(dec_out, outK, out);
}

// Round 2
// 19487.823 us; speedup vs baseline: 1.3632x; 1.3632x over previous
//
#include <hip/hip_runtime.h>

// Problem constants (reference: B,T,V,E,H = 16,64,32000,256,1024)
#define B_ 16
#define T_ 64
#define V_ 32000
#define E_ 256
#define H_ 1024
#define G4_ (4 * H_)      // 4096 gate width
#define KE_ (E_ + H_)     // 1280 encoder GEMM K
#define KD_ (E_ + 2*H_)   // 2304 decoder GEMM K
#define NKS_ 32           // k-splits for enc/dec GEMMs
#define KSE_ (KE_ / NKS_) // 40  rows per k-split (encoder)
#define KSD_ (KD_ / NKS_) // 72  rows per k-split (decoder)

typedef unsigned short ushort_t;
typedef unsigned int uint_t;

__device__ __forceinline__ float b2f(ushort_t u) {
    return __uint_as_float(((uint_t)u) << 16);
}
__device__ __forceinline__ ushort_t f2b(float f) {
    uint_t u = __float_as_uint(f);
    u = (u + 0x7fffu + ((u >> 16) & 1u)) >> 16;   // round-to-nearest-even
    return (ushort_t)u;
}
__device__ __forceinline__ float sigf(float x) {
    return 1.f / (1.f + expf(-x));
}

// ---------------------------------------------------------------------------
// Split-K semaphores, FIXED memory ordering (round-1 post-mortem):
//  - arrive: __syncthreads (drains all block stores to L2) + ONE release-RMW
//    by thread 0 (single buffer_wbl2). No __threadfence.
//  - wait: RELAXED spin (atomic loads read the coherence point, NO per-poll
//    L2 invalidate), then ONE acquire fence after exit.
// Round 1's acquire-in-spin emitted buffer_inv sc1 per poll across 64-256
// blocks -> ~43us/barrier + L2 annihilation. This is the coop-groups protocol.
// Deadlock-safe: 512-block grids @ launch_bounds(256,2) and 256-block grids
// are fully resident (proven by round-1 passing).
// ---------------------------------------------------------------------------
__device__ __forceinline__ void block_arrive(int* cnt) {
    __syncthreads();
    if (threadIdx.x == 0)
        __hip_atomic_fetch_add(cnt, 1, __ATOMIC_RELEASE, __HIP_MEMORY_SCOPE_AGENT);
}
__device__ __forceinline__ void block_wait(int* cnt, int target) {
    if (threadIdx.x == 0) {
        while (__hip_atomic_load(cnt, __ATOMIC_RELAXED, __HIP_MEMORY_SCOPE_AGENT) < target)
            __builtin_amdgcn_s_sleep(8);
        __builtin_amdgcn_fence(__ATOMIC_ACQUIRE, "agent");   // one L1/L2 inv
    }
    __syncthreads();
}
__device__ __forceinline__ void grid_barrier(int* cnt, int target) {
    block_arrive(cnt);
    block_wait(cnt, target);
}

// ---------------------------------------------------------------------------
// Zero-init fp32 state (hbuf x2, c, attn = 4*16384 floats) + 256 counters.
// ---------------------------------------------------------------------------
__global__ __launch_bounds__(256) void init_kernel(float* __restrict__ state,
                                                   int* __restrict__ cnts)
{
    const int i = blockIdx.x * 256 + threadIdx.x;
    if (i < 4 * B_ * H_) state[i] = 0.f;
    if (i < 256) cnts[i] = 0;
}

// ---------------------------------------------------------------------------
// Encoder step: split-K GEMM (grid 512 = 16 colchunk x 32 ksplit) with
// fused gates tail (blocks ks>=28 wait for all 512 partials, then run the
// 64-block gates domain). float4 x-loads; FMA order per k unchanged.
// ---------------------------------------------------------------------------
__global__ __launch_bounds__(256, 2) void enc_step_kernel(
    const float* __restrict__ emb, const int* __restrict__ enc_in,
    const float* __restrict__ Wk, const float* __restrict__ bias,
    const int* __restrict__ enc_len, const float* __restrict__ h_in,
    float* __restrict__ h_out, float* __restrict__ c,
    float* __restrict__ memory, float* __restrict__ zpart,
    int* __restrict__ cnt, int t)
{
    const int tid = threadIdx.x;
    const int cc = blockIdx.x & 15;
    const int ks = blockIdx.x >> 4;           // 0..31
    const int col = cc * 256 + tid;
    const int k0 = ks * KSE_;

    int vidx[16];
    #pragma unroll
    for (int b = 0; b < 16; ++b) vidx[b] = enc_in[b * T_ + t];

    float acc[16];
    #pragma unroll
    for (int b = 0; b < 16; ++b) acc[b] = 0.f;

    for (int g = 0; g < KSE_ / 4; ++g) {
        const int k = k0 + g * 4;
        const float* wp = Wk + (size_t)k * G4_ + col;
        const float w0 = wp[0];
        const float w1 = wp[G4_];
        const float w2 = wp[2 * G4_];
        const float w3 = wp[3 * G4_];
        if (k < E_) {     // groups never straddle: boundaries are x4
            #pragma unroll
            for (int b = 0; b < 16; ++b) {
                const float4 xv = *(const float4*)(emb + (size_t)vidx[b] * E_ + k);
                acc[b] = fmaf(xv.x, w0, acc[b]);
                acc[b] = fmaf(xv.y, w1, acc[b]);
                acc[b] = fmaf(xv.z, w2, acc[b]);
                acc[b] = fmaf(xv.w, w3, acc[b]);
            }
        } else {
            const float* hp = h_in + (k - E_);
            #pragma unroll
            for (int b = 0; b < 16; ++b) {
                const float4 xv = *(const float4*)(hp + b * H_);
                acc[b] = fmaf(xv.x, w0, acc[b]);
                acc[b] = fmaf(xv.y, w1, acc[b]);
                acc[b] = fmaf(xv.z, w2, acc[b]);
                acc[b] = fmaf(xv.w, w3, acc[b]);
            }
        }
    }
    #pragma unroll
    for (int b = 0; b < 16; ++b)
        zpart[(size_t)(ks * 16 + b) * G4_ + col] = acc[b];

    block_arrive(cnt);
    if (ks < 28) return;                       // 448 producer-only blocks exit
    block_wait(cnt, 512);

    // ---- fused gates (64 tail blocks = 16384 threads, 1 elem each) ----
    const int tb = (ks - 28) * 16 + cc;        // 0..63
    const int idx = tb * 256 + tid;
    const int b = idx >> 10, hu = idx & 1023;
    float z[4];
    #pragma unroll
    for (int g = 0; g < 4; ++g) {
        float s0 = bias[g * H_ + hu], s1 = 0.f, s2 = 0.f, s3 = 0.f;
        #pragma unroll
        for (int kss = 0; kss < NKS_; kss += 4) {
            s0 += zpart[(size_t)((kss + 0) * 16 + b) * G4_ + g * H_ + hu];
            s1 += zpart[(size_t)((kss + 1) * 16 + b) * G4_ + g * H_ + hu];
            s2 += zpart[(size_t)((kss + 2) * 16 + b) * G4_ + g * H_ + hu];
            s3 += zpart[(size_t)((kss + 3) * 16 + b) * G4_ + g * H_ + hu];
        }
        z[g] = (s0 + s1) + (s2 + s3);
    }
    const float cold = c[b * H_ + hu];
    const float cn = cold * sigf(z[2] + 1.f) + sigf(z[0]) * tanhf(z[1]);
    const float hn = tanhf(cn) * sigf(z[3]);
    const bool valid = t < enc_len[b];
    h_out[b * H_ + hu] = valid ? hn : h_in[b * H_ + hu];
    c[b * H_ + hu]     = valid ? cn : cold;
    memory[((size_t)b * T_ + t) * H_ + hu] = valid ? hn : 0.f;
}

// ---------------------------------------------------------------------------
// keys = memory[1024,1024] @ Wm. Grid 256 = (64 rowtile, 4 cc), float4 k.
// ---------------------------------------------------------------------------
__global__ __launch_bounds__(256) void keys_gemm_kernel(
    const float* __restrict__ memory, const float* __restrict__ Wm,
    float* __restrict__ keys)
{
    const int rt = blockIdx.x >> 2;
    const int cc = blockIdx.x & 3;
    const int col = cc * 256 + threadIdx.x;
    float acc[16];
    #pragma unroll
    for (int m = 0; m < 16; ++m) acc[m] = 0.f;
    for (int g = 0; g < H_ / 4; ++g) {
        const int k = g * 4;
        const float* wp = Wm + (size_t)k * H_ + col;
        const float w0 = wp[0], w1 = wp[H_], w2 = wp[2 * H_], w3 = wp[3 * H_];
        const float* mp = memory + (size_t)(rt * 16) * H_ + k;
        #pragma unroll
        for (int m = 0; m < 16; ++m) {
            const float4 xv = *(const float4*)(mp + (size_t)m * H_);
            acc[m] = fmaf(xv.x, w0, acc[m]);
            acc[m] = fmaf(xv.y, w1, acc[m]);
            acc[m] = fmaf(xv.z, w2, acc[m]);
            acc[m] = fmaf(xv.w, w3, acc[m]);
        }
    }
    #pragma unroll
    for (int m = 0; m < 16; ++m)
        keys[(size_t)(rt * 16 + m) * H_ + col] = acc[m];
}

// ---------------------------------------------------------------------------
// Decoder step: split-K GEMM (K=2304, grid 512) with fused gates tail.
// ---------------------------------------------------------------------------
__global__ __launch_bounds__(256, 2) void dec_step_kernel(
    const float* __restrict__ emb, const int* __restrict__ dec_in,
    const float* __restrict__ Wk, const float* __restrict__ bias,
    const float* __restrict__ attn, const float* __restrict__ h_in,
    float* __restrict__ h_out, float* __restrict__ c,
    float* __restrict__ zpart, int* __restrict__ cnt, int t)
{
    const int tid = threadIdx.x;
    const int cc = blockIdx.x & 15;
    const int ks = blockIdx.x >> 4;           // 0..31
    const int col = cc * 256 + tid;
    const int k0 = ks * KSD_;

    int vidx[16];
    #pragma unroll
    for (int b = 0; b < 16; ++b) vidx[b] = dec_in[b * T_ + t];

    float acc[16];
    #pragma unroll
    for (int b = 0; b < 16; ++b) acc[b] = 0.f;

    for (int g = 0; g < KSD_ / 4; ++g) {
        const int k = k0 + g * 4;
        const float* wp = Wk + (size_t)k * G4_ + col;
        const float w0 = wp[0];
        const float w1 = wp[G4_];
        const float w2 = wp[2 * G4_];
        const float w3 = wp[3 * G4_];
        if (k < E_) {
            #pragma unroll
            for (int b = 0; b < 16; ++b) {
                const float4 xv = *(const float4*)(emb + (size_t)vidx[b] * E_ + k);
                acc[b] = fmaf(xv.x, w0, acc[b]);
                acc[b] = fmaf(xv.y, w1, acc[b]);
                acc[b] = fmaf(xv.z, w2, acc[b]);
                acc[b] = fmaf(xv.w, w3, acc[b]);
            }
        } else {
            const float* xb = (k < E_ + H_) ? (attn + (k - E_))
                                            : (h_in + (k - E_ - H_));
            #pragma unroll
            for (int b = 0; b < 16; ++b) {
                const float4 xv = *(const float4*)(xb + b * H_);
                acc[b] = fmaf(xv.x, w0, acc[b]);
                acc[b] = fmaf(xv.y, w1, acc[b]);
                acc[b] = fmaf(xv.z, w2, acc[b]);
                acc[b] = fmaf(xv.w, w3, acc[b]);
            }
        }
    }
    #pragma unroll
    for (int b = 0; b < 16; ++b)
        zpart[(size_t)(ks * 16 + b) * G4_ + col] = acc[b];

    block_arrive(cnt);
    if (ks < 28) return;
    block_wait(cnt, 512);

    // ---- fused gates (no masking on carry) ----
    const int tb = (ks - 28) * 16 + cc;
    const int idx = tb * 256 + tid;
    const int b = idx >> 10, hu = idx & 1023;
    float z[4];
    #pragma unroll
    for (int g = 0; g < 4; ++g) {
        float s0 = bias[g * H_ + hu], s1 = 0.f, s2 = 0.f, s3 = 0.f;
        #pragma unroll
        for (int kss = 0; kss < NKS_; kss += 4) {
            s0 += zpart[(size_t)((kss + 0) * 16 + b) * G4_ + g * H_ + hu];
            s1 += zpart[(size_t)((kss + 1) * 16 + b) * G4_ + g * H_ + hu];
            s2 += zpart[(size_t)((kss + 2) * 16 + b) * G4_ + g * H_ + hu];
            s3 += zpart[(size_t)((kss + 3) * 16 + b) * G4_ + g * H_ + hu];
        }
        z[g] = (s0 + s1) + (s2 + s3);
    }
    const float cold = c[b * H_ + hu];
    const float cn = cold * sigf(z[2] + 1.f) + sigf(z[0]) * tanhf(z[1]);
    const float hn = tanhf(cn) * sigf(z[3]);
    h_out[b * H_ + hu] = hn;
    c[b * H_ + hu] = cn;
}

// ---------------------------------------------------------------------------
// Fused attention mega-kernel, 4 grid barriers (was 5):
//   A: q partials (256 blocks) -> A2: q finish (64) ->
//   BC: per-batch scores+softmax+context (16 blocks, fully in-block) ->
//   D: attn-out partials (256) -> E: finish (64).
// ---------------------------------------------------------------------------
__global__ __launch_bounds__(256, 2) void attn_mega_kernel(
    const float* __restrict__ h2, const float* __restrict__ Wq,
    float* __restrict__ qpart, float* __restrict__ q,
    const float* __restrict__ keys, const float* __restrict__ v_att,
    const float* __restrict__ memory, const int* __restrict__ enc_len,
    float* __restrict__ ctx, const float* __restrict__ attnK,
    float* __restrict__ apart, const int* __restrict__ dec_len,
    float* __restrict__ attn_state, float* __restrict__ dec_out,
    int* __restrict__ cnt, int t)
{
    const int tid = threadIdx.x;
    const int blk = blockIdx.x;
    __shared__ float sc[T_];
    __shared__ float al[T_];

    // ---- Phase A: q partials. 256 blocks = 4 cc x 64 ksplit (16 k each)
    {
        const int cc = blk & 3, ks = blk >> 2;
        const int col = cc * 256 + tid;
        const int k0 = ks * 16;
        float acc[16];
        #pragma unroll
        for (int b = 0; b < 16; ++b) acc[b] = 0.f;
        #pragma unroll
        for (int g = 0; g < 4; ++g) {
            const int k = k0 + g * 4;
            const float* wp = Wq + (size_t)k * H_ + col;
            const float w0 = wp[0], w1 = wp[H_], w2 = wp[2 * H_], w3 = wp[3 * H_];
            #pragma unroll
            for (int b = 0; b < 16; ++b) {
                const float4 xv = *(const float4*)(h2 + b * H_ + k);
                acc[b] = fmaf(xv.x, w0, acc[b]);
                acc[b] = fmaf(xv.y, w1, acc[b]);
                acc[b] = fmaf(xv.z, w2, acc[b]);
                acc[b] = fmaf(xv.w, w3, acc[b]);
            }
        }
        #pragma unroll
        for (int b = 0; b < 16; ++b)
            qpart[(size_t)(ks * 16 + b) * H_ + col] = acc[b];
    }
    grid_barrier(cnt, 256);

    // ---- Phase A2: q finish (blocks 0..63)
    if (blk < 64) {
        const int idx = blk * 256 + tid;
        const int b = idx >> 10, col = idx & 1023;
        float s0 = 0.f, s1 = 0.f, s2 = 0.f, s3 = 0.f;
        #pragma unroll
        for (int ks = 0; ks < 64; ks += 4) {
            s0 += qpart[(size_t)((ks + 0) * 16 + b) * H_ + col];
            s1 += qpart[(size_t)((ks + 1) * 16 + b) * H_ + col];
            s2 += qpart[(size_t)((ks + 2) * 16 + b) * H_ + col];
            s3 += qpart[(size_t)((ks + 3) * 16 + b) * H_ + col];
        }
        q[idx] = (s0 + s1) + (s2 + s3);
    }
    grid_barrier(cnt, 512);

    // ---- Phase BC: per-batch scores + masked softmax + context (blocks 0..15)
    if (blk < 16) {
        const int b = blk;
        const int wv = tid >> 6, lane = tid & 63;
        const float* qp = q + b * H_;
        for (int tt = wv; tt < T_; tt += 4) {        // 16 t per wave
            const float* kp = keys + ((size_t)b * T_ + tt) * H_;
            float s = 0.f;
            #pragma unroll
            for (int j = 0; j < 16; ++j) {
                const int h = lane + j * 64;
                s += tanhf(kp[h] + qp[h]) * v_att[h];
            }
            #pragma unroll
            for (int off = 32; off; off >>= 1) s += __shfl_xor(s, off);
            if (lane == 0) sc[tt] = s;
        }
        __syncthreads();
        if (tid < 64) {
            const int len = enc_len[b];
            float s = (tid < len) ? sc[tid] : -1e9f;
            float m = s;
            #pragma unroll
            for (int off = 32; off; off >>= 1) m = fmaxf(m, __shfl_xor(m, off));
            const float e = expf(s - m);
            float sum = e;
            #pragma unroll
            for (int off = 32; off; off >>= 1) sum += __shfl_xor(sum, off);
            al[tid] = e / sum;
        }
        __syncthreads();
        #pragma unroll
        for (int i = 0; i < 4; ++i) {
            const int col = tid + i * 256;
            const float* mp = memory + (size_t)b * T_ * H_ + col;
            float a0 = 0.f, a1 = 0.f, a2 = 0.f, a3 = 0.f;
            #pragma unroll
            for (int t2 = 0; t2 < T_; t2 += 4) {
                a0 = fmaf(al[t2 + 0], mp[(size_t)(t2 + 0) * H_], a0);
                a1 = fmaf(al[t2 + 1], mp[(size_t)(t2 + 1) * H_], a1);
                a2 = fmaf(al[t2 + 2], mp[(size_t)(t2 + 2) * H_], a2);
                a3 = fmaf(al[t2 + 3], mp[(size_t)(t2 + 3) * H_], a3);
            }
            ctx[b * H_ + col] = (a0 + a1) + (a2 + a3);
        }
    }
    grid_barrier(cnt, 768);

    // ---- Phase D: attn-out partials: [h2|ctx](K=2048) @ attnK, 64 ksplits
    {
        const int cc = blk & 3, ks = blk >> 2;
        const int col = cc * 256 + tid;
        const int k0 = ks * 32;
        float acc[16];
        #pragma unroll
        for (int b = 0; b < 16; ++b) acc[b] = 0.f;
        #pragma unroll
        for (int g = 0; g < 8; ++g) {
            const int k = k0 + g * 4;
            const float* wp = attnK + (size_t)k * H_ + col;
            const float w0 = wp[0], w1 = wp[H_], w2 = wp[2 * H_], w3 = wp[3 * H_];
            const float* xb = (k < H_) ? (h2 + k) : (ctx + (k - H_));
            #pragma unroll
            for (int b = 0; b < 16; ++b) {
                const float4 xv = *(const float4*)(xb + b * H_);
                acc[b] = fmaf(xv.x, w0, acc[b]);
                acc[b] = fmaf(xv.y, w1, acc[b]);
                acc[b] = fmaf(xv.z, w2, acc[b]);
                acc[b] = fmaf(xv.w, w3, acc[b]);
            }
        }
        #pragma unroll
        for (int b = 0; b < 16; ++b)
            apart[(size_t)(ks * 16 + b) * H_ + col] = acc[b];
    }
    grid_barrier(cnt, 1024);

    // ---- Phase E: finish attn2 -> attn state + dec_out (blocks 0..63)
    if (blk < 64) {
        const int idx = blk * 256 + tid;
        const int b = idx >> 10, col = idx & 1023;
        float s0 = 0.f, s1 = 0.f, s2 = 0.f, s3 = 0.f;
        #pragma unroll
        for (int ks = 0; ks < 64; ks += 4) {
            s0 += apart[(size_t)((ks + 0) * 16 + b) * H_ + col];
            s1 += apart[(size_t)((ks + 1) * 16 + b) * H_ + col];
            s2 += apart[(size_t)((ks + 2) * 16 + b) * H_ + col];
            s3 += apart[(size_t)((ks + 3) * 16 + b) * H_ + col];
        }
        const float s = (s0 + s1) + (s2 + s3);
        attn_state[b * H_ + col] = s;
        dec_out[((size_t)b * T_ + t) * H_ + col] = (t >= dec_len[b]) ? 0.f : s;
    }
}

// ---------------------------------------------------------------------------
// logits = dec_out(fp32 [1024,1024]) @ out_kernel(fp32 [1024,32000]) -> fp32.
// Split-bf16: D = ah*bh + ah*bl + al*bh. MFMA 16x16x32_bf16, 64x64 tile.
// LDS stride padded 40 -> 44 ushorts: start banks l*22%32 all-distinct for
// the 16-lane fragment reads -> 4-way conflicts drop to ~2-way (free).
// ---------------------------------------------------------------------------
typedef __attribute__((ext_vector_type(8))) short short8;
typedef __attribute__((ext_vector_type(4))) float float4v;

__global__ __launch_bounds__(256) void logits_kernel(
    const float* __restrict__ A, const float* __restrict__ Bw,
    float* __restrict__ out)
{
    __shared__ __align__(16) ushort_t Ah[64][44];
    __shared__ __align__(16) ushort_t Al[64][44];
    __shared__ __align__(16) ushort_t Bh[64][44];   // transposed: [n][k]
    __shared__ __align__(16) ushort_t Bl[64][44];
    const int tid = threadIdx.x;
    const int m0 = blockIdx.x * 64;
    const int n0 = blockIdx.y * 64;
    const int wv = tid >> 6, lane = tid & 63;
    const int ml = lane & 15, quad = lane >> 4;

    float4v acc[4];
    #pragma unroll
    for (int nn = 0; nn < 4; ++nn) acc[nn] = (float4v){0.f, 0.f, 0.f, 0.f};

    for (int kb = 0; kb < 1024; kb += 32) {
        __syncthreads();
        {   // stage A: 64 rows x 32 k fp32 -> hi/lo bf16
            const int r = tid >> 2, c0 = (tid & 3) * 8;
            const float* ap = A + (size_t)(m0 + r) * 1024 + kb + c0;
            #pragma unroll
            for (int i = 0; i < 8; ++i) {
                const float f = ap[i];
                const ushort_t hi = f2b(f);
                Ah[r][c0 + i] = hi;
                Al[r][c0 + i] = f2b(f - b2f(hi));
            }
        }
        {   // stage B transposed: coalesced rows, fp32 -> hi/lo bf16
            const int cB = tid & 63, kq = tid >> 6;
            #pragma unroll
            for (int i = 0; i < 8; ++i) {
                const int k = kq * 8 + i;
                const float f = Bw[(size_t)(kb + k) * V_ + n0 + cB];
                const ushort_t hi = f2b(f);
                Bh[cB][k] = hi;
                Bl[cB][k] = f2b(f - b2f(hi));
            }
        }
        __syncthreads();
        const short8 afh = *(const short8*)&Ah[wv * 16 + ml][quad * 8];
        const short8 afl = *(const short8*)&Al[wv * 16 + ml][quad * 8];
        #pragma unroll
        for (int nn = 0; nn < 4; ++nn) {
            const short8 bfh = *(const short8*)&Bh[nn * 16 + ml][quad * 8];
            const short8 bfl = *(const short8*)&Bl[nn * 16 + ml][quad * 8];
            acc[nn] = __builtin_amdgcn_mfma_f32_16x16x32_bf16(afh, bfh, acc[nn], 0, 0, 0);
            acc[nn] = __builtin_amdgcn_mfma_f32_16x16x32_bf16(afh, bfl, acc[nn], 0, 0, 0);
            acc[nn] = __builtin_amdgcn_mfma_f32_16x16x32_bf16(afl, bfh, acc[nn], 0, 0, 0);
        }
    }
    #pragma unroll
    for (int nn = 0; nn < 4; ++nn) {
        #pragma unroll
        for (int rg = 0; rg < 4; ++rg) {
            const int row = m0 + wv * 16 + quad * 4 + rg;
            const int colo = n0 + nn * 16 + ml;
            out[(size_t)row * V_ + colo] = acc[nn][rg];
        }
    }
}

// ---------------------------------------------------------------------------
extern "C" void kernel_launch(void* const* d_in, const int* in_sizes, int n_in,
                              void* d_out, int out_size, void* d_ws, size_t ws_size,
                              hipStream_t stream) {
    (void)in_sizes; (void)n_in; (void)out_size; (void)ws_size;
    const int*   enc_in  = (const int*)d_in[0];
    const int*   dec_in  = (const int*)d_in[1];
    const int*   enc_len = (const int*)d_in[2];
    const int*   dec_len = (const int*)d_in[3];
    const float* emb     = (const float*)d_in[4];
    const float* encK    = (const float*)d_in[5];
    const float* encB    = (const float*)d_in[6];
    const float* decK    = (const float*)d_in[7];
    const float* decB    = (const float*)d_in[8];
    const float* Wm      = (const float*)d_in[9];
    const float* Wq      = (const float*)d_in[10];
    const float* v_att   = (const float*)d_in[11];
    const float* attnK   = (const float*)d_in[12];
    const float* outK    = (const float*)d_in[13];
    float* out = (float*)d_out;

    // fp32 workspace layout (~21.4 MB + 1KB counters). qpart/apart alias
    // zpart (phases are sequential: zpart dead after fused gates; qpart dead
    // after phase A2; apart lives in zpart's second half).
    float* hbuf    = (float*)d_ws;                      // 2 x [16,1024]
    float* cbuf    = hbuf + 2 * B_ * H_;                // [16,1024]
    float* attn    = cbuf + B_ * H_;                    // [16,1024]
    float* ctx     = attn + B_ * H_;                    // [16,1024]
    float* q       = ctx + B_ * H_;                     // [16,1024]
    float* scores  = q + B_ * H_;                       // [16,64] (unused now)
    float* memory  = scores + B_ * T_;                  // [16,64,1024]
    float* keys    = memory + (size_t)B_ * T_ * H_;     // [16,64,1024]
    float* dec_out = keys + (size_t)B_ * T_ * H_;       // [1024,1024]
    float* zpart   = dec_out + (size_t)B_ * T_ * H_;    // [32][16][4096] = 8MB
    float* qpart   = zpart;                             // [64][16][1024] alias
    float* apart   = zpart + (size_t)64 * B_ * H_;      // [64][16][1024] alias
    int*   cnts    = (int*)(zpart + (size_t)NKS_ * B_ * G4_);  // 256 ints

    // zero fp32 recurrent state (ws poisoned 0xAA) + semaphore counters
    init_kernel<<<256, 256, 0, stream>>>((float*)d_ws, cnts);

    for (int t = 0; t < T_; ++t) {
        float* h_in  = hbuf + (t & 1) * B_ * H_;
        float* h_out = hbuf + ((t + 1) & 1) * B_ * H_;
        enc_step_kernel<<<512, 256, 0, stream>>>(emb, enc_in, encK, encB, enc_len,
                                                 h_in, h_out, cbuf, memory, zpart,
                                                 cnts + t, t);
    }
    keys_gemm_kernel<<<256, 256, 0, stream>>>(memory, Wm, keys);

    for (int t = 0; t < T_; ++t) {
        float* h_in = hbuf + (t & 1) * B_ * H_;
        float* h2   = hbuf + ((t + 1) & 1) * B_ * H_;
        dec_step_kernel<<<512, 256, 0, stream>>>(emb, dec_in, decK, decB, attn,
                                                 h_in, h2, cbuf, zpart,
                                                 cnts + 64 + t, t);
        attn_mega_kernel<<<256, 256, 0, stream>>>(h2, Wq, qpart, q, keys, v_att,
                                                  memory, enc_len, ctx,
                                                  attnK, apart, dec_len, attn,
                                                  dec_out, cnts + 128 + t, t);
    }

    logits_kernel<<<dim3(16, 500), 256, 0, stream>>>(dec_out, outK, out);
}

// Round 3
// 16020.358 us; speedup vs baseline: 1.6582x; 1.2164x over previous
//
#include <hip/hip_runtime.h>

// Problem constants (reference: B,T,V,E,H = 16,64,32000,256,1024)
#define B_ 16
#define T_ 64
#define V_ 32000
#define E_ 256
#define H_ 1024
#define G4_ (4 * H_)      // 4096 gate width
#define KE_ (E_ + H_)     // 1280 encoder GEMM K
#define KD_ (E_ + 2*H_)   // 2304 decoder GEMM K
#define NKS_ 32           // k-splits for enc/dec GEMMs
#define KSE_ (KE_ / NKS_) // 40  rows per k-split (encoder)
#define KSD_ (KD_ / NKS_) // 72  rows per k-split (decoder)

typedef unsigned short ushort_t;
typedef unsigned int uint_t;
typedef __attribute__((ext_vector_type(8))) short short8;
typedef __attribute__((ext_vector_type(4))) float float4v;

__device__ __forceinline__ float b2f(ushort_t u) {
    return __uint_as_float(((uint_t)u) << 16);
}
__device__ __forceinline__ ushort_t f2b(float f) {
    uint_t u = __float_as_uint(f);
    u = (u + 0x7fffu + ((u >> 16) & 1u)) >> 16;   // round-to-nearest-even
    return (ushort_t)u;
}
__device__ __forceinline__ float sigf(float x) {
    return 1.f / (1.f + expf(-x));
}

// ---------------------------------------------------------------------------
// NOTE (rounds 1-2 post-mortem): persistent-kernel grid barriers cost ~32us
// each on MI355X (per-block release-RMW -> buffer_wbl2 storm + acquire L2
// invalidate re-streams weights every phase). Kernel-launch boundaries are
// CHEAPER (~10us incl. work overlap). This version is multi-kernel again.
// ---------------------------------------------------------------------------

// Zero-init fp32 state: hbuf x2, c, attn = 4*16384 floats.
__global__ __launch_bounds__(256) void init_kernel(float* __restrict__ p, int n)
{
    int i = blockIdx.x * 256 + threadIdx.x;
    if (i < n) p[i] = 0.f;
}

// ---------------------------------------------------------------------------
// Encoder LSTM GEMM (split-K partials). Grid 512 = (16 colchunk, 32 ksplit).
// float4 over k (FMA order per k identical to scalar -> bit-identical).
// ---------------------------------------------------------------------------
__global__ __launch_bounds__(256) void enc_gemm_kernel(
    const float* __restrict__ emb, const int* __restrict__ enc_in,
    const float* __restrict__ Wk, const float* __restrict__ h_in,
    float* __restrict__ zpart, int t)
{
    const int cc = blockIdx.x & 15;
    const int ks = blockIdx.x >> 4;           // 0..31
    const int col = cc * 256 + threadIdx.x;
    const int k0 = ks * KSE_;

    int vidx[16];
    #pragma unroll
    for (int b = 0; b < 16; ++b) vidx[b] = enc_in[b * T_ + t];

    float acc[16];
    #pragma unroll
    for (int b = 0; b < 16; ++b) acc[b] = 0.f;

    for (int g = 0; g < KSE_ / 4; ++g) {
        const int k = k0 + g * 4;
        const float* wp = Wk + (size_t)k * G4_ + col;
        const float w0 = wp[0];
        const float w1 = wp[G4_];
        const float w2 = wp[2 * G4_];
        const float w3 = wp[3 * G4_];
        if (k < E_) {     // groups never straddle: boundaries are x4
            #pragma unroll
            for (int b = 0; b < 16; ++b) {
                const float4 xv = *(const float4*)(emb + (size_t)vidx[b] * E_ + k);
                acc[b] = fmaf(xv.x, w0, acc[b]);
                acc[b] = fmaf(xv.y, w1, acc[b]);
                acc[b] = fmaf(xv.z, w2, acc[b]);
                acc[b] = fmaf(xv.w, w3, acc[b]);
            }
        } else {
            const float* hp = h_in + (k - E_);
            #pragma unroll
            for (int b = 0; b < 16; ++b) {
                const float4 xv = *(const float4*)(hp + b * H_);
                acc[b] = fmaf(xv.x, w0, acc[b]);
                acc[b] = fmaf(xv.y, w1, acc[b]);
                acc[b] = fmaf(xv.z, w2, acc[b]);
                acc[b] = fmaf(xv.w, w3, acc[b]);
            }
        }
    }
    #pragma unroll
    for (int b = 0; b < 16; ++b)
        zpart[((size_t)(ks * 16 + b)) * G4_ + col] = acc[b];
}

// ---------------------------------------------------------------------------
// Encoder gates: reduce 32 partials + bias, LSTM activations, masked update.
// ---------------------------------------------------------------------------
__global__ __launch_bounds__(256) void enc_gates_kernel(
    const float* __restrict__ zpart, const float* __restrict__ bias,
    const int* __restrict__ enc_len, const float* __restrict__ h_in,
    float* __restrict__ h_out, float* __restrict__ c,
    float* __restrict__ memory, int t)
{
    const int idx = blockIdx.x * 256 + threadIdx.x;   // 0..16383
    const int b = idx >> 10, hu = idx & 1023;
    float z[4];
    #pragma unroll
    for (int g = 0; g < 4; ++g) {
        float s0 = bias[g * H_ + hu], s1 = 0.f, s2 = 0.f, s3 = 0.f;
        #pragma unroll
        for (int ks = 0; ks < NKS_; ks += 4) {
            s0 += zpart[((size_t)((ks + 0) * 16 + b)) * G4_ + g * H_ + hu];
            s1 += zpart[((size_t)((ks + 1) * 16 + b)) * G4_ + g * H_ + hu];
            s2 += zpart[((size_t)((ks + 2) * 16 + b)) * G4_ + g * H_ + hu];
            s3 += zpart[((size_t)((ks + 3) * 16 + b)) * G4_ + g * H_ + hu];
        }
        z[g] = (s0 + s1) + (s2 + s3);
    }
    const float cold = c[b * H_ + hu];
    const float cn = cold * sigf(z[2] + 1.f) + sigf(z[0]) * tanhf(z[1]);
    const float hn = tanhf(cn) * sigf(z[3]);
    const bool valid = t < enc_len[b];
    h_out[b * H_ + hu] = valid ? hn : h_in[b * H_ + hu];
    c[b * H_ + hu]     = valid ? cn : cold;
    memory[((size_t)b * T_ + t) * H_ + hu] = valid ? hn : 0.f;
}

// ---------------------------------------------------------------------------
// keys = memory[1024,1024] @ Wm. Grid 256 = (64 rowtile, 4 cc), float4 k.
// ---------------------------------------------------------------------------
__global__ __launch_bounds__(256) void keys_gemm_kernel(
    const float* __restrict__ memory, const float* __restrict__ Wm,
    float* __restrict__ keys)
{
    const int rt = blockIdx.x >> 2;
    const int cc = blockIdx.x & 3;
    const int col = cc * 256 + threadIdx.x;
    float acc[16];
    #pragma unroll
    for (int m = 0; m < 16; ++m) acc[m] = 0.f;
    for (int g = 0; g < H_ / 4; ++g) {
        const int k = g * 4;
        const float* wp = Wm + (size_t)k * H_ + col;
        const float w0 = wp[0], w1 = wp[H_], w2 = wp[2 * H_], w3 = wp[3 * H_];
        const float* mp = memory + (size_t)(rt * 16) * H_ + k;
        #pragma unroll
        for (int m = 0; m < 16; ++m) {
            const float4 xv = *(const float4*)(mp + (size_t)m * H_);
            acc[m] = fmaf(xv.x, w0, acc[m]);
            acc[m] = fmaf(xv.y, w1, acc[m]);
            acc[m] = fmaf(xv.z, w2, acc[m]);
            acc[m] = fmaf(xv.w, w3, acc[m]);
        }
    }
    #pragma unroll
    for (int m = 0; m < 16; ++m)
        keys[(size_t)(rt * 16 + m) * H_ + col] = acc[m];
}

// ---------------------------------------------------------------------------
// Decoder LSTM GEMM (split-K partials). x = [emb | attn | h], K=2304.
// ---------------------------------------------------------------------------
__global__ __launch_bounds__(256) void dec_gemm_kernel(
    const float* __restrict__ emb, const int* __restrict__ dec_in,
    const float* __restrict__ Wk, const float* __restrict__ attn,
    const float* __restrict__ h_in, float* __restrict__ zpart, int t)
{
    const int cc = blockIdx.x & 15;
    const int ks = blockIdx.x >> 4;           // 0..31
    const int col = cc * 256 + threadIdx.x;
    const int k0 = ks * KSD_;

    int vidx[16];
    #pragma unroll
    for (int b = 0; b < 16; ++b) vidx[b] = dec_in[b * T_ + t];

    float acc[16];
    #pragma unroll
    for (int b = 0; b < 16; ++b) acc[b] = 0.f;

    for (int g = 0; g < KSD_ / 4; ++g) {
        const int k = k0 + g * 4;
        const float* wp = Wk + (size_t)k * G4_ + col;
        const float w0 = wp[0];
        const float w1 = wp[G4_];
        const float w2 = wp[2 * G4_];
        const float w3 = wp[3 * G4_];
        if (k < E_) {
            #pragma unroll
            for (int b = 0; b < 16; ++b) {
                const float4 xv = *(const float4*)(emb + (size_t)vidx[b] * E_ + k);
                acc[b] = fmaf(xv.x, w0, acc[b]);
                acc[b] = fmaf(xv.y, w1, acc[b]);
                acc[b] = fmaf(xv.z, w2, acc[b]);
                acc[b] = fmaf(xv.w, w3, acc[b]);
            }
        } else {
            const float* xb = (k < E_ + H_) ? (attn + (k - E_))
                                            : (h_in + (k - E_ - H_));
            #pragma unroll
            for (int b = 0; b < 16; ++b) {
                const float4 xv = *(const float4*)(xb + b * H_);
                acc[b] = fmaf(xv.x, w0, acc[b]);
                acc[b] = fmaf(xv.y, w1, acc[b]);
                acc[b] = fmaf(xv.z, w2, acc[b]);
                acc[b] = fmaf(xv.w, w3, acc[b]);
            }
        }
    }
    #pragma unroll
    for (int b = 0; b < 16; ++b)
        zpart[((size_t)(ks * 16 + b)) * G4_ + col] = acc[b];
}

// ---------------------------------------------------------------------------
// Decoder gates (no masking on carry). Grid 64 x 256.
// ---------------------------------------------------------------------------
__global__ __launch_bounds__(256) void dec_gates_kernel(
    const float* __restrict__ zpart, const float* __restrict__ bias,
    float* __restrict__ h_out, float* __restrict__ c)
{
    const int idx = blockIdx.x * 256 + threadIdx.x;
    const int b = idx >> 10, hu = idx & 1023;
    float z[4];
    #pragma unroll
    for (int g = 0; g < 4; ++g) {
        float s0 = bias[g * H_ + hu], s1 = 0.f, s2 = 0.f, s3 = 0.f;
        #pragma unroll
        for (int ks = 0; ks < NKS_; ks += 4) {
            s0 += zpart[((size_t)((ks + 0) * 16 + b)) * G4_ + g * H_ + hu];
            s1 += zpart[((size_t)((ks + 1) * 16 + b)) * G4_ + g * H_ + hu];
            s2 += zpart[((size_t)((ks + 2) * 16 + b)) * G4_ + g * H_ + hu];
            s3 += zpart[((size_t)((ks + 3) * 16 + b)) * G4_ + g * H_ + hu];
        }
        z[g] = (s0 + s1) + (s2 + s3);
    }
    const float cold = c[b * H_ + hu];
    const float cn = cold * sigf(z[2] + 1.f) + sigf(z[0]) * tanhf(z[1]);
    const float hn = tanhf(cn) * sigf(z[3]);
    h_out[b * H_ + hu] = hn;
    c[b * H_ + hu] = cn;
}

// ---------------------------------------------------------------------------
// q = h2 @ Wq, full-K per thread. Grid 64 = (16 b, 4 cc).
// Replaces query_gemm + query_finish (2 kernels -> 1).
// ---------------------------------------------------------------------------
__global__ __launch_bounds__(256) void q_kernel(
    const float* __restrict__ h2, const float* __restrict__ Wq,
    float* __restrict__ q)
{
    const int b = blockIdx.x >> 2, cc = blockIdx.x & 3;
    const int col = cc * 256 + threadIdx.x;
    const float* hp = h2 + b * H_;
    float acc = 0.f;
    for (int g = 0; g < H_ / 4; ++g) {
        const int k = g * 4;
        const float* wp = Wq + (size_t)k * H_ + col;
        const float4 xv = *(const float4*)(hp + k);
        acc = fmaf(xv.x, wp[0], acc);
        acc = fmaf(xv.y, wp[H_], acc);
        acc = fmaf(xv.z, wp[2 * H_], acc);
        acc = fmaf(xv.w, wp[3 * H_], acc);
    }
    q[b * H_ + col] = acc;
}

// ---------------------------------------------------------------------------
// Per-batch scores + masked softmax + context (round-2 BC phase, verified).
// Grid 16 blocks (one per batch), 256 threads. Replaces attn_scores +
// softmax_ctx (2 kernels -> 1, and 1024-block scores grid -> in-block).
// ---------------------------------------------------------------------------
__global__ __launch_bounds__(256) void sc_ctx_kernel(
    const float* __restrict__ q, const float* __restrict__ keys,
    const float* __restrict__ v_att, const float* __restrict__ memory,
    const int* __restrict__ enc_len, float* __restrict__ ctx)
{
    const int b = blockIdx.x;
    const int tid = threadIdx.x;
    const int wv = tid >> 6, lane = tid & 63;
    __shared__ float sc[T_];
    __shared__ float al[T_];
    const float* qp = q + b * H_;
    for (int tt = wv; tt < T_; tt += 4) {        // 16 t per wave
        const float* kp = keys + ((size_t)b * T_ + tt) * H_;
        float s = 0.f;
        #pragma unroll
        for (int j = 0; j < 16; ++j) {
            const int h = lane + j * 64;
            s += tanhf(kp[h] + qp[h]) * v_att[h];
        }
        #pragma unroll
        for (int off = 32; off; off >>= 1) s += __shfl_xor(s, off);
        if (lane == 0) sc[tt] = s;
    }
    __syncthreads();
    if (tid < 64) {
        const int len = enc_len[b];
        float s = (tid < len) ? sc[tid] : -1e9f;
        float m = s;
        #pragma unroll
        for (int off = 32; off; off >>= 1) m = fmaxf(m, __shfl_xor(m, off));
        const float e = expf(s - m);
        float sum = e;
        #pragma unroll
        for (int off = 32; off; off >>= 1) sum += __shfl_xor(sum, off);
        al[tid] = e / sum;
    }
    __syncthreads();
    #pragma unroll
    for (int i = 0; i < 4; ++i) {
        const int col = tid + i * 256;
        const float* mp = memory + (size_t)b * T_ * H_ + col;
        float a0 = 0.f, a1 = 0.f, a2 = 0.f, a3 = 0.f;
        #pragma unroll
        for (int t2 = 0; t2 < T_; t2 += 4) {
            a0 = fmaf(al[t2 + 0], mp[(size_t)(t2 + 0) * H_], a0);
            a1 = fmaf(al[t2 + 1], mp[(size_t)(t2 + 1) * H_], a1);
            a2 = fmaf(al[t2 + 2], mp[(size_t)(t2 + 2) * H_], a2);
            a3 = fmaf(al[t2 + 3], mp[(size_t)(t2 + 3) * H_], a3);
        }
        ctx[b * H_ + col] = (a0 + a1) + (a2 + a3);
    }
}

// ---------------------------------------------------------------------------
// attn2 partials: [h2|ctx](K=2048) @ attn_kernel, split-K 32. Grid 128.
// ---------------------------------------------------------------------------
__global__ __launch_bounds__(256) void attnout_gemm_kernel(
    const float* __restrict__ h2, const float* __restrict__ ctx,
    const float* __restrict__ attn_k, float* __restrict__ apart)
{
    const int cc = blockIdx.x & 3;
    const int ks = blockIdx.x >> 2;     // 0..31
    const int col = cc * 256 + threadIdx.x;
    const int k0 = ks * 64;
    float acc[16];
    #pragma unroll
    for (int b = 0; b < 16; ++b) acc[b] = 0.f;
    #pragma unroll
    for (int g = 0; g < 16; ++g) {
        const int k = k0 + g * 4;
        const float* wp = attn_k + (size_t)k * H_ + col;
        const float w0 = wp[0], w1 = wp[H_], w2 = wp[2 * H_], w3 = wp[3 * H_];
        const float* xb = (k < H_) ? (h2 + k) : (ctx + (k - H_));
        #pragma unroll
        for (int b = 0; b < 16; ++b) {
            const float4 xv = *(const float4*)(xb + b * H_);
            acc[b] = fmaf(xv.x, w0, acc[b]);
            acc[b] = fmaf(xv.y, w1, acc[b]);
            acc[b] = fmaf(xv.z, w2, acc[b]);
            acc[b] = fmaf(xv.w, w3, acc[b]);
        }
    }
    #pragma unroll
    for (int b = 0; b < 16; ++b)
        apart[((size_t)(ks * 16 + b)) * H_ + col] = acc[b];
}

// ---------------------------------------------------------------------------
// attn_out finish: reduce 32 partials -> attn state + dec_out. Grid 64.
// ---------------------------------------------------------------------------
__global__ __launch_bounds__(256) void attnout_finish_kernel(
    const float* __restrict__ apart, const int* __restrict__ dec_len,
    float* __restrict__ attn_state, float* __restrict__ dec_out, int t)
{
    const int idx = blockIdx.x * 256 + threadIdx.x;
    const int b = idx >> 10, col = idx & 1023;
    float s0 = 0.f, s1 = 0.f, s2 = 0.f, s3 = 0.f;
    #pragma unroll
    for (int ks = 0; ks < 32; ks += 4) {
        s0 += apart[((size_t)((ks + 0) * 16 + b)) * H_ + col];
        s1 += apart[((size_t)((ks + 1) * 16 + b)) * H_ + col];
        s2 += apart[((size_t)((ks + 2) * 16 + b)) * H_ + col];
        s3 += apart[((size_t)((ks + 3) * 16 + b)) * H_ + col];
    }
    const float s = (s0 + s1) + (s2 + s3);
    attn_state[b * H_ + col] = s;
    const bool fin = t >= dec_len[b];
    dec_out[((size_t)b * T_ + t) * H_ + col] = fin ? 0.f : s;
}

// ---------------------------------------------------------------------------
// Logits prep 1: split out_kernel fp32 [k][n] -> bf16 hi/lo TRANSPOSED [n][k]
// (fragment-ready layout). LDS transpose, 64x64 tiles. Grid 16*500.
// ---------------------------------------------------------------------------
__global__ __launch_bounds__(256) void bsplit_kernel(
    const float* __restrict__ Bw, ushort_t* __restrict__ Bh_t,
    ushort_t* __restrict__ Bl_t)
{
    __shared__ ushort_t Th[64][65];
    __shared__ ushort_t Tl[64][65];
    const int k0 = (blockIdx.x & 15) * 64;      // 16 k-tiles
    const int n0 = (blockIdx.x >> 4) * 64;      // 500 n-tiles
    const int tid = threadIdx.x;
    {   // read: lane = n (coalesced), 16 k rows per thread
        const int nl = tid & 63, kb = tid >> 6;
        for (int i = 0; i < 16; ++i) {
            const int kl = kb + i * 4;
            const float f = Bw[(size_t)(k0 + kl) * V_ + n0 + nl];
            const ushort_t hi = f2b(f);
            Th[kl][nl] = hi;
            Tl[kl][nl] = f2b(f - b2f(hi));
        }
    }
    __syncthreads();
    {   // write: thread owns row r (n), 16 contiguous k -> 2x short8 stores
        const int r = tid >> 2, c0 = (tid & 3) * 16;
        short8 vh0, vh1, vl0, vl1;
        #pragma unroll
        for (int j = 0; j < 8; ++j) {
            vh0[j] = (short)Th[c0 + j][r];
            vh1[j] = (short)Th[c0 + 8 + j][r];
            vl0[j] = (short)Tl[c0 + j][r];
            vl1[j] = (short)Tl[c0 + 8 + j][r];
        }
        ushort_t* ph = Bh_t + (size_t)(n0 + r) * 1024 + k0 + c0;
        ushort_t* pl = Bl_t + (size_t)(n0 + r) * 1024 + k0 + c0;
        *(short8*)ph = vh0;
        *(short8*)(ph + 8) = vh1;
        *(short8*)pl = vl0;
        *(short8*)(pl + 8) = vl1;
    }
}

// ---------------------------------------------------------------------------
// Logits prep 2: split dec_out fp32 [m][k] -> bf16 hi/lo [m][k]. Grid 512.
// ---------------------------------------------------------------------------
__global__ __launch_bounds__(256) void asplit_kernel(
    const float* __restrict__ A, ushort_t* __restrict__ Ah_g,
    ushort_t* __restrict__ Al_g)
{
    const size_t i0 = ((size_t)blockIdx.x * 256 + threadIdx.x) * 8;
    const float4 f0 = *(const float4*)(A + i0);
    const float4 f1 = *(const float4*)(A + i0 + 4);
    float f[8] = {f0.x, f0.y, f0.z, f0.w, f1.x, f1.y, f1.z, f1.w};
    short8 vh, vl;
    #pragma unroll
    for (int j = 0; j < 8; ++j) {
        const ushort_t hi = f2b(f[j]);
        vh[j] = (short)hi;
        vl[j] = (short)f2b(f[j] - b2f(hi));
    }
    *(short8*)(Ah_g + i0) = vh;
    *(short8*)(Al_g + i0) = vl;
}

// ---------------------------------------------------------------------------
// Logits from precomputed splits: NO LDS, NO conversion — direct global
// fragment loads + MFMA. BM=128 (B re-streamed 8x instead of 16x), BN=64.
// 4 waves, each owns 32 rows (2 m-subtiles). Grid (8, 500).
// Same f2b + MFMA term order as before -> bit-identical output.
// ---------------------------------------------------------------------------
__global__ __launch_bounds__(256) void logits_pre_kernel(
    const ushort_t* __restrict__ Ah_g, const ushort_t* __restrict__ Al_g,
    const ushort_t* __restrict__ Bh_t, const ushort_t* __restrict__ Bl_t,
    float* __restrict__ out)
{
    const int tid = threadIdx.x;
    const int m0 = blockIdx.x * 128;
    const int n0 = blockIdx.y * 64;
    const int w = tid >> 6, lane = tid & 63;
    const int ml = lane & 15, quad = lane >> 4;

    float4v acc[2][4];
    #pragma unroll
    for (int ms = 0; ms < 2; ++ms)
        #pragma unroll
        for (int nn = 0; nn < 4; ++nn) acc[ms][nn] = (float4v){0.f, 0.f, 0.f, 0.f};

    const size_t arow0 = (size_t)(m0 + w * 32 + ml) * 1024;
    const size_t arow1 = (size_t)(m0 + w * 32 + 16 + ml) * 1024;

    for (int kb = 0; kb < 1024; kb += 32) {
        const int ko = kb + quad * 8;
        const short8 ah0 = *(const short8*)(Ah_g + arow0 + ko);
        const short8 al0 = *(const short8*)(Al_g + arow0 + ko);
        const short8 ah1 = *(const short8*)(Ah_g + arow1 + ko);
        const short8 al1 = *(const short8*)(Al_g + arow1 + ko);
        #pragma unroll
        for (int nn = 0; nn < 4; ++nn) {
            const size_t brow = (size_t)(n0 + nn * 16 + ml) * 1024 + ko;
            const short8 bfh = *(const short8*)(Bh_t + brow);
            const short8 bfl = *(const short8*)(Bl_t + brow);
            acc[0][nn] = __builtin_amdgcn_mfma_f32_16x16x32_bf16(ah0, bfh, acc[0][nn], 0, 0, 0);
            acc[0][nn] = __builtin_amdgcn_mfma_f32_16x16x32_bf16(ah0, bfl, acc[0][nn], 0, 0, 0);
            acc[0][nn] = __builtin_amdgcn_mfma_f32_16x16x32_bf16(al0, bfh, acc[0][nn], 0, 0, 0);
            acc[1][nn] = __builtin_amdgcn_mfma_f32_16x16x32_bf16(ah1, bfh, acc[1][nn], 0, 0, 0);
            acc[1][nn] = __builtin_amdgcn_mfma_f32_16x16x32_bf16(ah1, bfl, acc[1][nn], 0, 0, 0);
            acc[1][nn] = __builtin_amdgcn_mfma_f32_16x16x32_bf16(al1, bfh, acc[1][nn], 0, 0, 0);
        }
    }
    #pragma unroll
    for (int ms = 0; ms < 2; ++ms) {
        #pragma unroll
        for (int nn = 0; nn < 4; ++nn) {
            #pragma unroll
            for (int rg = 0; rg < 4; ++rg) {
                const int row = m0 + w * 32 + ms * 16 + quad * 4 + rg;
                const int colo = n0 + nn * 16 + ml;
                out[(size_t)row * V_ + colo] = acc[ms][nn][rg];
            }
        }
    }
}

// ---------------------------------------------------------------------------
// Fallback logits (in-kernel conversion, 64x64) — used if ws too small.
// ---------------------------------------------------------------------------
__global__ __launch_bounds__(256) void logits_kernel(
    const float* __restrict__ A, const float* __restrict__ Bw,
    float* __restrict__ out)
{
    __shared__ __align__(16) ushort_t Ah[64][44];
    __shared__ __align__(16) ushort_t Al[64][44];
    __shared__ __align__(16) ushort_t Bh[64][44];   // transposed: [n][k]
    __shared__ __align__(16) ushort_t Bl[64][44];
    const int tid = threadIdx.x;
    const int m0 = blockIdx.x * 64;
    const int n0 = blockIdx.y * 64;
    const int wv = tid >> 6, lane = tid & 63;
    const int ml = lane & 15, quad = lane >> 4;

    float4v acc[4];
    #pragma unroll
    for (int nn = 0; nn < 4; ++nn) acc[nn] = (float4v){0.f, 0.f, 0.f, 0.f};

    for (int kb = 0; kb < 1024; kb += 32) {
        __syncthreads();
        {   // stage A
            const int r = tid >> 2, c0 = (tid & 3) * 8;
            const float* ap = A + (size_t)(m0 + r) * 1024 + kb + c0;
            #pragma unroll
            for (int i = 0; i < 8; ++i) {
                const float f = ap[i];
                const ushort_t hi = f2b(f);
                Ah[r][c0 + i] = hi;
                Al[r][c0 + i] = f2b(f - b2f(hi));
            }
        }
        {   // stage B transposed
            const int cB = tid & 63, kq = tid >> 6;
            #pragma unroll
            for (int i = 0; i < 8; ++i) {
                const int k = kq * 8 + i;
                const float f = Bw[(size_t)(kb + k) * V_ + n0 + cB];
                const ushort_t hi = f2b(f);
                Bh[cB][k] = hi;
                Bl[cB][k] = f2b(f - b2f(hi));
            }
        }
        __syncthreads();
        const short8 afh = *(const short8*)&Ah[wv * 16 + ml][quad * 8];
        const short8 afl = *(const short8*)&Al[wv * 16 + ml][quad * 8];
        #pragma unroll
        for (int nn = 0; nn < 4; ++nn) {
            const short8 bfh = *(const short8*)&Bh[nn * 16 + ml][quad * 8];
            const short8 bfl = *(const short8*)&Bl[nn * 16 + ml][quad * 8];
            acc[nn] = __builtin_amdgcn_mfma_f32_16x16x32_bf16(afh, bfh, acc[nn], 0, 0, 0);
            acc[nn] = __builtin_amdgcn_mfma_f32_16x16x32_bf16(afh, bfl, acc[nn], 0, 0, 0);
            acc[nn] = __builtin_amdgcn_mfma_f32_16x16x32_bf16(afl, bfh, acc[nn], 0, 0, 0);
        }
    }
    #pragma unroll
    for (int nn = 0; nn < 4; ++nn) {
        #pragma unroll
        for (int rg = 0; rg < 4; ++rg) {
            const int row = m0 + wv * 16 + quad * 4 + rg;
            const int colo = n0 + nn * 16 + ml;
            out[(size_t)row * V_ + colo] = acc[nn][rg];
        }
    }
}

// ---------------------------------------------------------------------------
extern "C" void kernel_launch(void* const* d_in, const int* in_sizes, int n_in,
                              void* d_out, int out_size, void* d_ws, size_t ws_size,
                              hipStream_t stream) {
    (void)in_sizes; (void)n_in; (void)out_size;
    const int*   enc_in  = (const int*)d_in[0];
    const int*   dec_in  = (const int*)d_in[1];
    const int*   enc_len = (const int*)d_in[2];
    const int*   dec_len = (const int*)d_in[3];
    const float* emb     = (const float*)d_in[4];
    const float* encK    = (const float*)d_in[5];
    const float* encB    = (const float*)d_in[6];
    const float* decK    = (const float*)d_in[7];
    const float* decB    = (const float*)d_in[8];
    const float* Wm      = (const float*)d_in[9];
    const float* Wq      = (const float*)d_in[10];
    const float* v_att   = (const float*)d_in[11];
    const float* attnK   = (const float*)d_in[12];
    const float* outK    = (const float*)d_in[13];
    float* out = (float*)d_out;

    // fp32 workspace layout (base ~21.4 MB). apart aliases zpart (zpart dead
    // after gates). Optional bf16-split region after zpart (+135 MB), gated
    // on ws_size.
    float* hbuf    = (float*)d_ws;                      // 2 x [16,1024]
    float* cbuf    = hbuf + 2 * B_ * H_;                // [16,1024]
    float* attn    = cbuf + B_ * H_;                    // [16,1024]
    float* ctx     = attn + B_ * H_;                    // [16,1024]
    float* q       = ctx + B_ * H_;                     // [16,1024]
    float* scores  = q + B_ * H_;                       // [16,64] (unused)
    float* memory  = scores + B_ * T_;                  // [16,64,1024]
    float* keys    = memory + (size_t)B_ * T_ * H_;     // [16,64,1024]
    float* dec_out = keys + (size_t)B_ * T_ * H_;       // [1024,1024]
    float* zpart   = dec_out + (size_t)B_ * T_ * H_;    // [32][16][4096] = 8MB
    float* apart   = zpart;                             // [32][16][1024] alias
    float* base_end = zpart + (size_t)NKS_ * B_ * G4_;  // byte off 21368832

    ushort_t* Ah_g = (ushort_t*)base_end;               // [1024][1024] 2MB
    ushort_t* Al_g = Ah_g + (size_t)1024 * 1024;        // 2MB
    ushort_t* Bh_t = Al_g + (size_t)1024 * 1024;        // [32000][1024] 65.5MB
    ushort_t* Bl_t = Bh_t + (size_t)V_ * 1024;          // 65.5MB
    const size_t need = 21368832ull + 2ull * 2097152ull + 2ull * 65536000ull;
    const bool use_pre = ws_size >= need;

    // zero fp32 recurrent state (ws poisoned 0xAA): hbuf x2, c, attn
    const int ninit = 4 * B_ * H_;
    init_kernel<<<(ninit + 255) / 256, 256, 0, stream>>>((float*)d_ws, ninit);

    if (use_pre)   // one-time weight split (independent of the loops)
        bsplit_kernel<<<16 * 500, 256, 0, stream>>>(outK, Bh_t, Bl_t);

    for (int t = 0; t < T_; ++t) {
        float* h_in  = hbuf + (t & 1) * B_ * H_;
        float* h_out = hbuf + ((t + 1) & 1) * B_ * H_;
        enc_gemm_kernel<<<512, 256, 0, stream>>>(emb, enc_in, encK, h_in, zpart, t);
        enc_gates_kernel<<<64, 256, 0, stream>>>(zpart, encB, enc_len, h_in,
                                                 h_out, cbuf, memory, t);
    }
    keys_gemm_kernel<<<256, 256, 0, stream>>>(memory, Wm, keys);

    for (int t = 0; t < T_; ++t) {
        float* h_in = hbuf + (t & 1) * B_ * H_;
        float* h2   = hbuf + ((t + 1) & 1) * B_ * H_;
        dec_gemm_kernel<<<512, 256, 0, stream>>>(emb, dec_in, decK, attn, h_in, zpart, t);
        dec_gates_kernel<<<64, 256, 0, stream>>>(zpart, decB, h2, cbuf);
        q_kernel<<<64, 256, 0, stream>>>(h2, Wq, q);
        sc_ctx_kernel<<<16, 256, 0, stream>>>(q, keys, v_att, memory, enc_len, ctx);
        attnout_gemm_kernel<<<128, 256, 0, stream>>>(h2, ctx, attnK, apart);
        attnout_finish_kernel<<<64, 256, 0, stream>>>(apart, dec_len, attn, dec_out, t);
    }

    if (use_pre) {
        asplit_kernel<<<512, 256, 0, stream>>>(dec_out, Ah_g, Al_g);
        logits_pre_kernel<<<dim3(8, 500), 256, 0, stream>>>(Ah_g, Al_g, Bh_t, Bl_t, out);
    } else {
        logits_kernel<<<dim3(16, 500), 256, 0, stream>>>(dec_out, outK, out);
    }
}